// Round 5
// baseline (110680.176 us; speedup 1.0000x reference)
//
#include <hip/hip_runtime.h>
#include <stdint.h>

typedef unsigned int  u32;
typedef unsigned short u16;
typedef unsigned long long u64;

#define SEQ    8192
#define HID    1024
#define NL     5
#define NWG    256
#define TPB    256
#define PAIRS  20                 // (layer,unit) pairs per WG; NWG*PAIRS = NL*HID
#define RPW    20                 // gate-rows per wave (4 waves * 20 = 80 = PAIRS*4)
#define NVR    12                 // rows kept in VGPRs per wave
#define NLR    8                  // rows kept in LDS per wave (NVR+NLR == RPW)
#define WSTEPS (SEQ + NL - 1)     // 8196 wavefront steps
#define LWGS   52                 // producer WGs per layer
#define RING   16                 // slot ring depth (WAR slack = RING-2 = 14 steps)

// ---- workspace layout (bytes) ----
#define WS_X0    ((size_t)0)                        // 8192*512 u32 = 16 MiB (bf16 packed)
#define WS_H5    ((size_t)16*1024*1024)             // 16 MiB
#define WS_SLOT  ((size_t)32*1024*1024)             // 5*16*512 u64 = 320 KiB (pad 384 KiB)
#define WS_SYNC  (WS_SLOT + (size_t)384*1024)       // epochs[5] (128-B spaced); dtype flag @+2048
#define WS_NEED  (WS_SYNC + 4096)

// ---------------- helpers ----------------
__device__ __forceinline__ float bf2f(u16 v) { return __uint_as_float(((u32)v) << 16); }
__device__ __forceinline__ float bflo(u32 v) { return __uint_as_float(v << 16); }
__device__ __forceinline__ float bfhi(u32 v) { return __uint_as_float(v & 0xffff0000u); }

__device__ __forceinline__ u16 f2bf(float f) {            // round-to-nearest-even
  u32 u = __float_as_uint(f);
  u32 r = u + 0x7fffu + ((u >> 16) & 1u);
  return (u16)(r >> 16);
}
__device__ __forceinline__ float lrelu(float x) { return (x >= 0.f) ? x : 0.01f * x; }
__device__ __forceinline__ float sigm(float x)  { return 1.f / (1.f + __expf(-x)); }
__device__ __forceinline__ float tanh_f(float x) {
  float e = __expf(-2.f * fabsf(x));
  float t = (1.f - e) / (1.f + e);
  return (x >= 0.f) ? t : -t;
}

// software packed-bf16x2 dot (bit-exact unpack + f32 fma) — proven fallback
__device__ __forceinline__ float dot2bf(u32 w, u32 v, float acc) {
  return fmaf(bfhi(w), bfhi(v), fmaf(bflo(w), bflo(v), acc));
}

// hardware v_dot2_f32_bf16 — validated at runtime by k_detect before use
#if defined(__has_builtin)
#if __has_builtin(__builtin_amdgcn_fdot2_f32_bf16)
#define HAS_DOT2 1
typedef __bf16 bf16x2 __attribute__((ext_vector_type(2)));
__device__ __forceinline__ float hwdot2(u32 a, u32 b, float c) {
  union U { u32 u; bf16x2 v; };
  U x, y; x.u = a; y.u = b;
  return __builtin_amdgcn_fdot2_f32_bf16(x.v, y.v, c, false);
}
#endif
#endif
#ifndef HAS_DOT2
#define HAS_DOT2 0
__device__ __forceinline__ float hwdot2(u32 a, u32 b, float c) { return dot2bf(a, b, c); }
#endif

__device__ __forceinline__ u32 agent_load(const u32* p) {
  return __hip_atomic_load((u32*)p, __ATOMIC_RELAXED, __HIP_MEMORY_SCOPE_AGENT);
}
// 8-B LLC-coherent slot ops. A naturally-aligned 8-B store/load is one memory
// transaction, so tag (hi word) and data (lo word) are read/written together:
// tag == expected  =>  data word is the matching step's value. This IS the sync.
__device__ __forceinline__ u64 slot_load(const u64* p) {
  return __hip_atomic_load((u64*)p, __ATOMIC_RELAXED, __HIP_MEMORY_SCOPE_AGENT);
}
__device__ __forceinline__ void slot_store(u64* p, u64 v) {
  __hip_atomic_store(p, v, __ATOMIC_RELAXED, __HIP_MEMORY_SCOPE_AGENT);
}
__device__ __forceinline__ void epoch_add(u32* p) {
  (void)__hip_atomic_fetch_add(p, 1u, __ATOMIC_RELAXED, __HIP_MEMORY_SCOPE_AGENT);
}

// ---------------- K0: dtype probe + dot2 validation ----------------
__global__ void k_detect(const u32* __restrict__ w1, u32* __restrict__ flag) {
  int lane = threadIdx.x;       // 64 threads
  int cnt = 0;
#pragma unroll
  for (int i = 0; i < 4; ++i) {
    u32 w = w1[lane * 4 + i];
    u32 e = (w >> 23) & 0xffu;
    cnt += (e >= 100u && e <= 140u) ? 1 : 0;
  }
  cnt += __shfl_xor(cnt, 32); cnt += __shfl_xor(cnt, 16); cnt += __shfl_xor(cnt, 8);
  cnt += __shfl_xor(cnt, 4);  cnt += __shfl_xor(cnt, 2);  cnt += __shfl_xor(cnt, 1);
  if (lane == 0) {
    u32 f = (cnt > 128) ? 1u : 0u;
#if HAS_DOT2
    u32 a1 = (u32)f2bf(1.5f)   | ((u32)f2bf(-2.25f) << 16);
    u32 b1v = (u32)f2bf(0.5f)  | ((u32)f2bf(4.0f)   << 16);
    u32 a2 = (u32)f2bf(0.125f) | ((u32)f2bf(3.0f)   << 16);
    u32 b2v = (u32)f2bf(8.0f)  | ((u32)f2bf(-0.5f)  << 16);
    float t1 = hwdot2(a1, b1v, 1.0f);   // 1 + 0.75 - 9   = -7.25
    float t2 = hwdot2(a2, b2v, 0.5f);   // 0.5 + 1 - 1.5  = 0
    if (fabsf(t1 + 7.25f) < 1e-2f && fabsf(t2) < 1e-2f) f |= 2u;
#endif
    *flag = f;
  }
}

// ---------------- K1: X0 = leaky_relu(data_in @ w1.T + b1), stored packed bf16 ----------------
__global__ void __launch_bounds__(256) k_in(const void* __restrict__ din,
                                            const void* __restrict__ w1,
                                            const void* __restrict__ b1,
                                            u32* __restrict__ X0,
                                            const u32* __restrict__ flagp) {
  const u32 isf = *flagp & 1u;
  int t = blockIdx.x, tid = threadIdx.x;
  __shared__ float xs[64];
  if (isf) {
    if (tid < 64) xs[tid] = ((const float*)din)[(size_t)t * 64 + tid];
  } else {
    if (tid < 32) {
      u32 v = ((const u32*)din)[(size_t)t * 32 + tid];
      xs[2 * tid] = bflo(v); xs[2 * tid + 1] = bfhi(v);
    }
  }
  __syncthreads();
  float o[4];
#pragma unroll
  for (int r = 0; r < 4; ++r) {
    int i = tid * 4 + r;
    float a = 0.f;
    if (isf) {
      const float* wr = (const float*)w1 + (size_t)i * 64;
#pragma unroll
      for (int d = 0; d < 64; ++d) a = fmaf(wr[d], xs[d], a);
      a += ((const float*)b1)[i];
    } else {
      const u32* wr = (const u32*)w1 + (size_t)i * 32;
#pragma unroll
      for (int d = 0; d < 32; ++d) {
        u32 w = wr[d];
        a = fmaf(bflo(w), xs[2 * d], a);
        a = fmaf(bfhi(w), xs[2 * d + 1], a);
      }
      a += bf2f(((const u16*)b1)[i]);
    }
    o[r] = lrelu(a);
  }
  X0[(size_t)t * 512 + tid * 2]     = (u32)f2bf(o[0]) | ((u32)f2bf(o[1]) << 16);
  X0[(size_t)t * 512 + tid * 2 + 1] = (u32)f2bf(o[2]) | ((u32)f2bf(o[3]) << 16);
}

// ---------------- K2: persistent wavefront LSTM — tag-in-data push, batched polls ----------------
// Slot = u64 per h-pair: [tag=t (hi) | bf16x2 pair (lo)], slots[l][t&15][512].
// Publish: one 8-B fire-and-forget LLC store per pair (no drain, no flags).
// Consume: staging loads compare the tag inline; detection == data transfer.
// R5 changes vs R4 (protocol identical):
//  (a) poll pass is BATCHED: all 4-8 slot loads issued back-to-back (plain
//      unconditional loads, wave-uniform guards only), compares afterwards —
//      one pass ~= one LLC round-trip instead of 4-8 serialized RTs;
//  (b) both owned layers staged in ONE merged retry loop (spanning WGs no
//      longer serialize two full loops);
//  (c) WAR epoch check caches its horizon: one LLC load certifies ~14 steps.
// All spins share ONE global budget -> kernel is provably terminating.
__global__ void __launch_bounds__(TPB, 1) k_wave(const void* __restrict__ WihP,
                                                 const void* __restrict__ WhhP,
                                                 const void* __restrict__ bihP,
                                                 const void* __restrict__ bhhP,
                                                 const void* __restrict__ h0P,
                                                 const void* __restrict__ c0P,
                                                 const u32* __restrict__ X0,
                                                 u32* __restrict__ H5,
                                                 u64* slots64, u32* epochs,
                                                 const u32* __restrict__ flagp) {
  const u32 dfl = *flagp;
  const u32 isf = dfl & 1u;
  const bool ud2 = (dfl & 2u) != 0u;
  const int tid  = threadIdx.x;
  const int lane = tid & 63;
  const int wv   = tid >> 6;
  const int wg   = blockIdx.x;

  __shared__ u32   vlds[2][64 * 17];            // [layer-sel][lane*17 + d] (odd stride: conflict-free)
  __shared__ u32   wlds[4 * NLR * 1024];        // [wave][row][d4][lane][4] 128 KiB, b128-friendly
  __shared__ float zrow[80];

  // ---- load weights: rows 0..NVR-1 -> VGPRs, rows NVR..19 -> LDS ----
  u32 W[NVR][16];
#pragma unroll
  for (int i = 0; i < RPW; ++i) {
    int rr = wv * RPW + i;
    int p = rr >> 2, q = rr & 3;
    int g = wg * PAIRS + p;
    int lg = g >> 10, j = g & 1023;
    u32 tmp[16];
    if (isf) {
      const float* matf = (lane < 32) ? (const float*)WihP : (const float*)WhhP;
      const float4* s4 = (const float4*)(matf + ((size_t)(lg * 4096 + q * 1024 + j)) * 1024 + (lane & 31) * 32);
#pragma unroll
      for (int q4 = 0; q4 < 8; ++q4) {
        float4 f = s4[q4];
        tmp[q4 * 2]     = (u32)f2bf(f.x) | ((u32)f2bf(f.y) << 16);
        tmp[q4 * 2 + 1] = (u32)f2bf(f.z) | ((u32)f2bf(f.w) << 16);
      }
    } else {
      const u32* mat = (lane < 32) ? (const u32*)WihP : (const u32*)WhhP;
      const uint4* s4 = (const uint4*)(mat + ((size_t)(lg * 4096 + q * 1024 + j)) * 512 + (lane & 31) * 16);
      uint4 a0 = s4[0], a1 = s4[1], a2 = s4[2], a3 = s4[3];
      tmp[0]=a0.x; tmp[1]=a0.y; tmp[2]=a0.z;  tmp[3]=a0.w;
      tmp[4]=a1.x; tmp[5]=a1.y; tmp[6]=a1.z;  tmp[7]=a1.w;
      tmp[8]=a2.x; tmp[9]=a2.y; tmp[10]=a2.z; tmp[11]=a2.w;
      tmp[12]=a3.x;tmp[13]=a3.y;tmp[14]=a3.z; tmp[15]=a3.w;
    }
    if (i < NVR) {
#pragma unroll
      for (int d = 0; d < 16; ++d) W[i][d] = tmp[d];
    } else {
      u32* base = &wlds[(wv * NLR + (i - NVR)) * 1024];
#pragma unroll
      for (int d4 = 0; d4 < 4; ++d4) {
        uint4 v4 = make_uint4(tmp[d4*4], tmp[d4*4+1], tmp[d4*4+2], tmp[d4*4+3]);
        *(uint4*)&base[d4 * 256 + lane * 4] = v4;
      }
    }
  }

  // ---- per-unit state in wave0 registers (lane < PAIRS owns one unit) ----
  float cst = 0.f;
  float b0 = 0.f, b1g = 0.f, b2g = 0.f, b3g = 0.f;
  if (wv == 0 && lane < PAIRS) {
    int g = wg * PAIRS + lane, lg = g >> 10, j = g & 1023;
    cst = isf ? ((const float*)c0P)[lg * 1024 + j] : bf2f(((const u16*)c0P)[lg * 1024 + j]);
#pragma unroll
    for (int q = 0; q < 4; ++q) {
      int r = lg * 4096 + q * 1024 + j;
      float bb = isf ? (((const float*)bihP)[r] + ((const float*)bhhP)[r])
                     : (bf2f(((const u16*)bihP)[r]) + bf2f(((const u16*)bhhP)[r]));
      if (q == 0) b0 = bb; else if (q == 1) b1g = bb; else if (q == 2) b2g = bb; else b3g = bb;
    }
  }
  if (tid < PAIRS / 2) {          // h0 -> ring slot RING-1 (t = -1), tag = 0xFFFFFFFF
    int g = wg * PAIRS + 2 * tid, lg = g >> 10, j = g & 1023;
    u32 v;
    if (isf) {
      const float* h0f = (const float*)h0P;
      v = (u32)f2bf(h0f[lg * 1024 + j]) | ((u32)f2bf(h0f[lg * 1024 + j + 1]) << 16);
    } else {
      const u16* h0b = (const u16*)h0P;
      v = (u32)h0b[lg * 1024 + j] | ((u32)h0b[lg * 1024 + j + 1] << 16);
    }
    slot_store(&slots64[(size_t)(lg * RING + (RING - 1)) * 512 + (j >> 1)],
               ((u64)0xFFFFFFFFull << 32) | (u64)v);
  }
  // no init fence/flag needed: tags self-synchronize (stale tag => retry)

  const int l_lo = (wg * PAIRS) >> 10;
  const int l_hi = (wg * PAIRS + PAIRS - 1) >> 10;
  const bool span = (l_hi != l_lo);

  int budget = 20000000;                        // bounded polling: never hard-hang
  int war_until0 = RING - 2;                    // publishes certified through this step
  int war_until1 = RING - 2;

  for (int s = 0; s < WSTEPS; ++s) {
    // ---- merged batched staging for both owned layers (tag match = sync) ----
    {
      const int t0s = s - l_lo;
      const int t1s = s - l_hi;
      const bool a0 = (t0s >= 0) && (t0s < SEQ);
      const bool a1 = span && (t1s >= 0) && (t1s < SEQ);
      u32 okm = 0;
      u32 dat[8];
#pragma unroll
      for (int w = 0; w < 8; ++w) dat[w] = 0u;
      const u64* dummy = slots64;               // safe readable address
      const u64* bx0 = dummy; const u64* bh0 = dummy;
      const u64* bx1 = dummy; const u64* bh1 = dummy;
      const u32 ex0 = (u32)t0s, eh0 = (u32)(t0s - 1);
      const u32 ex1 = (u32)t1s, eh1 = (u32)(t1s - 1);
      if (a0) {
        bh0 = slots64 + (size_t)(l_lo * RING + ((t0s - 1) & (RING - 1))) * 512;
        if (l_lo > 0) {
          bx0 = slots64 + (size_t)((l_lo - 1) * RING + (t0s & (RING - 1))) * 512;
        } else {                                 // X0 is always fresh (prior kernel)
          dat[0] = X0[(size_t)t0s * 512 + tid];
          dat[1] = X0[(size_t)t0s * 512 + tid + 256];
          okm |= 3u;
        }
      } else okm |= 15u;
      if (a1) {                                  // spanning WG: layer below l_hi == l_lo
        bh1 = slots64 + (size_t)(l_hi * RING + ((t1s - 1) & (RING - 1))) * 512;
        bx1 = slots64 + (size_t)(l_lo * RING + (t1s & (RING - 1))) * 512;
      } else okm |= 15u << 4;

      int miss = 0;
      while (okm != 0xFFu) {
        // batched pass: issue ALL loads back-to-back, evaluate afterwards.
        u64 v0 = 0, v1 = 0, v2 = 0, v3 = 0, v4 = 0, v5 = 0, v6 = 0, v7 = 0;
        if (a0) {
          v0 = slot_load(bx0 + tid);
          v1 = slot_load(bx0 + tid + 256);
          v2 = slot_load(bh0 + tid);
          v3 = slot_load(bh0 + tid + 256);
        }
        if (a1) {
          v4 = slot_load(bx1 + tid);
          v5 = slot_load(bx1 + tid + 256);
          v6 = slot_load(bh1 + tid);
          v7 = slot_load(bh1 + tid + 256);
        }
        if (!(okm & 1u)   && (u32)(v0 >> 32) == ex0) { dat[0] = (u32)v0; okm |= 1u; }
        if (!(okm & 2u)   && (u32)(v1 >> 32) == ex0) { dat[1] = (u32)v1; okm |= 2u; }
        if (!(okm & 4u)   && (u32)(v2 >> 32) == eh0) { dat[2] = (u32)v2; okm |= 4u; }
        if (!(okm & 8u)   && (u32)(v3 >> 32) == eh0) { dat[3] = (u32)v3; okm |= 8u; }
        if (!(okm & 16u)  && (u32)(v4 >> 32) == ex1) { dat[4] = (u32)v4; okm |= 16u; }
        if (!(okm & 32u)  && (u32)(v5 >> 32) == ex1) { dat[5] = (u32)v5; okm |= 32u; }
        if (!(okm & 64u)  && (u32)(v6 >> 32) == eh1) { dat[6] = (u32)v6; okm |= 64u; }
        if (!(okm & 128u) && (u32)(v7 >> 32) == eh1) { dat[7] = (u32)v7; okm |= 128u; }
        if (--budget < 0) break;
        if (++miss >= 16) __builtin_amdgcn_s_sleep(1);   // stragglers only
      }
      if (a0) {
        vlds[0][((tid      ) >> 4) * 17 + ((tid      ) & 15)] = dat[0];
        vlds[0][((tid + 256) >> 4) * 17 + ((tid + 256) & 15)] = dat[1];
        vlds[0][((tid + 512) >> 4) * 17 + ((tid + 512) & 15)] = dat[2];
        vlds[0][((tid + 768) >> 4) * 17 + ((tid + 768) & 15)] = dat[3];
      }
      if (a1) {
        vlds[1][((tid      ) >> 4) * 17 + ((tid      ) & 15)] = dat[4];
        vlds[1][((tid + 256) >> 4) * 17 + ((tid + 256) & 15)] = dat[5];
        vlds[1][((tid + 512) >> 4) * 17 + ((tid + 512) & 15)] = dat[6];
        vlds[1][((tid + 768) >> 4) * 17 + ((tid + 768) & 15)] = dat[7];
      }
    }
    __syncthreads();            // B: vlds ready

    // ---- 20 row dots per wave (12 VGPR rows + 8 LDS rows) ----
    {
      int curl = -1;
      u32 vreg[16];
#pragma unroll
      for (int i = 0; i < RPW; ++i) {
        int rr = wv * RPW + i;
        int p = rr >> 2;
        int g = wg * PAIRS + p;
        int lg = g >> 10;
        int t = s - lg;
        if (t >= 0 && t < SEQ) {
          if (lg != curl) {
            curl = lg;
            const u32* vb = &vlds[lg - l_lo][lane * 17];
#pragma unroll
            for (int d = 0; d < 16; ++d) vreg[d] = vb[d];
          }
          float a0 = 0.f, a1 = 0.f, a2 = 0.f, a3 = 0.f;
          if (i < NVR) {
            if (ud2) {
#pragma unroll
              for (int d = 0; d < 16; d += 4) {
                a0 = hwdot2(W[i][d],   vreg[d],   a0);
                a1 = hwdot2(W[i][d+1], vreg[d+1], a1);
                a2 = hwdot2(W[i][d+2], vreg[d+2], a2);
                a3 = hwdot2(W[i][d+3], vreg[d+3], a3);
              }
            } else {
#pragma unroll
              for (int d = 0; d < 16; d += 4) {
                a0 = fmaf(bflo(W[i][d]),   bflo(vreg[d]),   a0);
                a0 = fmaf(bfhi(W[i][d]),   bfhi(vreg[d]),   a0);
                a1 = fmaf(bflo(W[i][d+1]), bflo(vreg[d+1]), a1);
                a1 = fmaf(bfhi(W[i][d+1]), bfhi(vreg[d+1]), a1);
                a2 = fmaf(bflo(W[i][d+2]), bflo(vreg[d+2]), a2);
                a2 = fmaf(bfhi(W[i][d+2]), bfhi(vreg[d+2]), a2);
                a3 = fmaf(bflo(W[i][d+3]), bflo(vreg[d+3]), a3);
                a3 = fmaf(bfhi(W[i][d+3]), bfhi(vreg[d+3]), a3);
              }
            }
          } else {
            const uint4* wl = (const uint4*)&wlds[(wv * NLR + (i - NVR)) * 1024 + lane * 4];
#pragma unroll
            for (int d4 = 0; d4 < 4; ++d4) {
              uint4 w4 = wl[d4 * 64];
              if (ud2) {
                a0 = hwdot2(w4.x, vreg[d4*4+0], a0);
                a1 = hwdot2(w4.y, vreg[d4*4+1], a1);
                a2 = hwdot2(w4.z, vreg[d4*4+2], a2);
                a3 = hwdot2(w4.w, vreg[d4*4+3], a3);
              } else {
                a0 = fmaf(bflo(w4.x), bflo(vreg[d4*4+0]), a0);
                a0 = fmaf(bfhi(w4.x), bfhi(vreg[d4*4+0]), a0);
                a1 = fmaf(bflo(w4.y), bflo(vreg[d4*4+1]), a1);
                a1 = fmaf(bfhi(w4.y), bfhi(vreg[d4*4+1]), a1);
                a2 = fmaf(bflo(w4.z), bflo(vreg[d4*4+2]), a2);
                a2 = fmaf(bfhi(w4.z), bfhi(vreg[d4*4+2]), a2);
                a3 = fmaf(bflo(w4.w), bflo(vreg[d4*4+3]), a3);
                a3 = fmaf(bfhi(w4.w), bfhi(vreg[d4*4+3]), a3);
              }
            }
          }
          float r = (a0 + a1) + (a2 + a3);
          r += __shfl_xor(r, 32);
          r += __shfl_xor(r, 16);
          r += __shfl_xor(r, 8);
          r += __shfl_xor(r, 4);
          r += __shfl_xor(r, 2);
          r += __shfl_xor(r, 1);
          if (lane == 0) zrow[rr] = r;
        }
      }
    }
    __syncthreads();            // C: zrow ready

    // ---- wave0: WAR guard (cached horizon) + gates + publish + epochs ----
    if (wv == 0) {
      // WAR: overwriting slot (t&15) requires layer L+1 done with step s-15,
      // i.e. epoch[L+1] >= 52*(s-14). One load certifies through step
      // floor(E/52)+14; reload only when s passes the cached horizon.
      if ((l_lo + 1) < NL && s > war_until0) {
        for (;;) {
          u32 E = agent_load(&epochs[(l_lo + 1) * 32]);
          int until = (int)(E / 52u) + (RING - 2);
          if (until >= s) { war_until0 = until; break; }
          if (--budget < 0) { war_until0 = s; break; }
          __builtin_amdgcn_s_sleep(2);
        }
      }
      if (span && (l_hi + 1) < NL && s > war_until1) {
        for (;;) {
          u32 E = agent_load(&epochs[(l_hi + 1) * 32]);
          int until = (int)(E / 52u) + (RING - 2);
          if (until >= s) { war_until1 = until; break; }
          if (--budget < 0) { war_until1 = s; break; }
          __builtin_amdgcn_s_sleep(2);
        }
      }
      u16 hb = 0;
      int g = wg * PAIRS + lane;     // valid for lane < PAIRS
      int lg = g >> 10;
      int t = s - lg;
      bool act = (lane < PAIRS) && (t >= 0) && (t < SEQ);
      if (act) {
        float zi = zrow[lane * 4 + 0] + b0;
        float zf = zrow[lane * 4 + 1] + b1g;
        float zg = zrow[lane * 4 + 2] + b2g;
        float zo = zrow[lane * 4 + 3] + b3g;
        float ig = sigm(zi), fg = sigm(zf), gg = tanh_f(zg), og = sigm(zo);
        float c = fg * cst + ig * gg;
        cst = c;
        hb = f2bf(og * tanh_f(c));
      }
      u16 hnb = (u16)__shfl_xor((int)hb, 1);
      if (act && ((lane & 1) == 0)) {
        int j = g & 1023;
        u32 v = (u32)hb | ((u32)hnb << 16);
        slot_store(&slots64[(size_t)(lg * RING + (t & (RING - 1))) * 512 + (j >> 1)],
                   ((u64)(u32)t << 32) | (u64)v);      // fire-and-forget
        if (lg == NL - 1) H5[(size_t)t * 512 + (j >> 1)] = v;
      }
      if (lane == 0) {               // step s complete for owned layers
        epoch_add(&epochs[l_lo * 32]);
        if (l_hi != l_lo) epoch_add(&epochs[l_hi * 32]);
      }
    }
  }
}

// ---------------- K3: out = tanh(leaky_relu(h5) @ w2.T + b2) ----------------
__global__ void __launch_bounds__(256) k_out(const u32* __restrict__ H5,
                                             const void* __restrict__ w2,
                                             const void* __restrict__ b2,
                                             void* __restrict__ out,
                                             const u32* __restrict__ flagp) {
  const u32 isf = *flagp & 1u;
  int t = blockIdx.x, tid = threadIdx.x;
  __shared__ float hs[1024];
  __shared__ float part[256];
#pragma unroll
  for (int r = 0; r < 2; ++r) {
    int idx = tid + r * 256;
    u32 v = H5[(size_t)t * 512 + idx];
    hs[2 * idx]     = lrelu(bflo(v));
    hs[2 * idx + 1] = lrelu(bfhi(v));
  }
  __syncthreads();
  int n = tid & 63, qq = tid >> 6;
  float a = 0.f;
  if (isf) {
    const float* wr = (const float*)w2 + (size_t)n * 1024 + qq * 256;
    const float* hb = &hs[qq * 256];
#pragma unroll
    for (int d = 0; d < 256; ++d) a = fmaf(wr[d], hb[d], a);
  } else {
    const u32* wr = (const u32*)w2 + (size_t)n * 512 + qq * 128;
    const float* hb = &hs[qq * 256];
#pragma unroll
    for (int d = 0; d < 128; ++d) {
      u32 w = wr[d];
      a = fmaf(bflo(w), hb[2 * d], a);
      a = fmaf(bfhi(w), hb[2 * d + 1], a);
    }
  }
  part[tid] = a;
  __syncthreads();
  if (tid < 64) {
    float bb = isf ? ((const float*)b2)[tid] : bf2f(((const u16*)b2)[tid]);
    float y = part[tid] + part[tid + 64] + part[tid + 128] + part[tid + 192] + bb;
    float r = tanh_f(y);
    if (isf) ((float*)out)[(size_t)t * 64 + tid] = r;
    else     ((u16*)out)[(size_t)t * 64 + tid] = f2bf(r);
  }
}

// ---------------- launcher ----------------
extern "C" void kernel_launch(void* const* d_in, const int* in_sizes, int n_in,
                              void* d_out, int out_size, void* d_ws, size_t ws_size,
                              hipStream_t stream) {
  (void)in_sizes; (void)n_in; (void)out_size;
  if (ws_size < WS_NEED) return;

  const void* din = d_in[0];
  const void* w1  = d_in[1];
  const void* b1  = d_in[2];
  const void* Wih = d_in[3];
  const void* Whh = d_in[4];
  const void* bih = d_in[5];
  const void* bhh = d_in[6];
  const void* w2  = d_in[7];
  const void* b2  = d_in[8];
  const void* h0  = d_in[9];
  const void* c0  = d_in[10];

  char* ws = (char*)d_ws;
  u32* X0     = (u32*)(ws + WS_X0);
  u32* H5     = (u32*)(ws + WS_H5);
  u64* slot   = (u64*)(ws + WS_SLOT);
  u32* epochs = (u32*)(ws + WS_SYNC);
  u32* dflag  = (u32*)(ws + WS_SYNC + 2048);

  // slot tags must not alias any valid tag (t in [0,SEQ) or 0xFFFFFFFF):
  // 0xAAAAAAAA is neither. memset per launch kills cross-run tag aliasing.
  hipMemsetAsync(slot, 0xAA, (size_t)NL * RING * 512 * 8, stream);
  hipMemsetAsync(epochs, 0, 4096, stream);     // epochs + dtype word
  k_detect<<<1, 64, 0, stream>>>((const u32*)w1, dflag);
  k_in  <<<SEQ, 256, 0, stream>>>(din, w1, b1, X0, dflag);
  k_wave<<<NWG, TPB, 0, stream>>>(Wih, Whh, bih, bhh, h0, c0, X0, H5, slot, epochs, dflag);
  k_out <<<SEQ, 256, 0, stream>>>(H5, w2, b2, d_out, dflag);
}

// Round 6
// 108351.636 us; speedup vs baseline: 1.0215x; 1.0215x over previous
//
#include <hip/hip_runtime.h>
#include <stdint.h>

typedef unsigned int  u32;
typedef unsigned short u16;
typedef unsigned long long u64;

#define SEQ    8192
#define HID    1024
#define NL     5
#define NWG    256
#define TPB    256
#define PAIRS  20                 // (layer,unit) pairs per WG; NWG*PAIRS = NL*HID
#define RPW    20                 // gate-rows per wave (4 waves * 20 = 80 = PAIRS*4)
#define NVR    12                 // rows kept in VGPRs per wave
#define NLR    8                  // rows kept in LDS per wave (NVR+NLR == RPW)
#define SKEW   2                  // inter-layer step lag (2 => x publishable 1 step early)
#define WSTEPS (SEQ + SKEW * (NL - 1))   // 8200 wavefront steps
#define LWGS   52                 // producer WGs per layer
#define RING   16                 // slot ring depth

// ---- workspace layout (bytes) ----
#define WS_X0    ((size_t)0)                        // 8192*512 u32 = 16 MiB (bf16 packed)
#define WS_H5    ((size_t)16*1024*1024)             // 16 MiB
#define WS_SLOT  ((size_t)32*1024*1024)             // 5*16*256 granules * 16 B = 320 KiB
#define WS_SYNC  (WS_SLOT + (size_t)384*1024)       // epochs[5] (128-B spaced); dtype flag @+2048
#define WS_NEED  (WS_SYNC + 4096)

#define VIDX(w) ((((w) >> 4) * 17) + ((w) & 15))    // vlds bank-spread mapping

// ---------------- helpers ----------------
__device__ __forceinline__ float bf2f(u16 v) { return __uint_as_float(((u32)v) << 16); }
__device__ __forceinline__ float bflo(u32 v) { return __uint_as_float(v << 16); }
__device__ __forceinline__ float bfhi(u32 v) { return __uint_as_float(v & 0xffff0000u); }

__device__ __forceinline__ u16 f2bf(float f) {            // round-to-nearest-even
  u32 u = __float_as_uint(f);
  u32 r = u + 0x7fffu + ((u >> 16) & 1u);
  return (u16)(r >> 16);
}
__device__ __forceinline__ float lrelu(float x) { return (x >= 0.f) ? x : 0.01f * x; }
__device__ __forceinline__ float sigm(float x)  { return 1.f / (1.f + __expf(-x)); }
__device__ __forceinline__ float tanh_f(float x) {
  float e = __expf(-2.f * fabsf(x));
  float t = (1.f - e) / (1.f + e);
  return (x >= 0.f) ? t : -t;
}

// software packed-bf16x2 dot (bit-exact unpack + f32 fma) — proven fallback
__device__ __forceinline__ float dot2bf(u32 w, u32 v, float acc) {
  return fmaf(bfhi(w), bfhi(v), fmaf(bflo(w), bflo(v), acc));
}

// hardware v_dot2_f32_bf16 — validated at runtime by k_detect before use
#if defined(__has_builtin)
#if __has_builtin(__builtin_amdgcn_fdot2_f32_bf16)
#define HAS_DOT2 1
typedef __bf16 bf16x2 __attribute__((ext_vector_type(2)));
__device__ __forceinline__ float hwdot2(u32 a, u32 b, float c) {
  union U { u32 u; bf16x2 v; };
  U x, y; x.u = a; y.u = b;
  return __builtin_amdgcn_fdot2_f32_bf16(x.v, y.v, c, false);
}
#endif
#endif
#ifndef HAS_DOT2
#define HAS_DOT2 0
__device__ __forceinline__ float hwdot2(u32 a, u32 b, float c) { return dot2bf(a, b, c); }
#endif

__device__ __forceinline__ u32 agent_load(const u32* p) {
  return __hip_atomic_load((u32*)p, __ATOMIC_RELAXED, __HIP_MEMORY_SCOPE_AGENT);
}
__device__ __forceinline__ void epoch_add(u32* p) {
  (void)__hip_atomic_fetch_add(p, 1u, __ATOMIC_RELAXED, __HIP_MEMORY_SCOPE_AGENT);
}

// 16-B LLC-coherent granule ops. A naturally-aligned dwordx4 within one cache
// line is a single memory transaction: tag (word0) and the two h-pairs travel
// together. tag == expected  =>  payload words are the matching step's values.
// (Store side proven correct by R1's passing run; load side is symmetric.)
typedef u32 u32x4_t __attribute__((ext_vector_type(4)));
__device__ __forceinline__ void llc_store4(u32* p, u32 tag, u32 a, u32 b) {
  u32x4_t q; q.x = tag; q.y = a; q.z = b; q.w = 0u;
  asm volatile("global_store_dwordx4 %0, %1, off sc0 sc1" : : "v"(p), "v"(q) : "memory");
}
__device__ __forceinline__ u32x4_t llc_load4(const u32* p) {
  u32x4_t r;
  asm volatile("global_load_dwordx4 %0, %1, off sc0 sc1" : "=v"(r) : "v"(p));
  return r;
}
__device__ __forceinline__ void vm_drain() {       // inline-asm loads: manual waitcnt
  asm volatile("s_waitcnt vmcnt(0)" ::: "memory");
}

__device__ __forceinline__ int first_wg(int l) { return (l << 10) / PAIRS; }  // {0,51,102,153,204}

// ---------------- K0: dtype probe + dot2 validation ----------------
__global__ void k_detect(const u32* __restrict__ w1, u32* __restrict__ flag) {
  int lane = threadIdx.x;       // 64 threads
  int cnt = 0;
#pragma unroll
  for (int i = 0; i < 4; ++i) {
    u32 w = w1[lane * 4 + i];
    u32 e = (w >> 23) & 0xffu;
    cnt += (e >= 100u && e <= 140u) ? 1 : 0;
  }
  cnt += __shfl_xor(cnt, 32); cnt += __shfl_xor(cnt, 16); cnt += __shfl_xor(cnt, 8);
  cnt += __shfl_xor(cnt, 4);  cnt += __shfl_xor(cnt, 2);  cnt += __shfl_xor(cnt, 1);
  if (lane == 0) {
    u32 f = (cnt > 128) ? 1u : 0u;
#if HAS_DOT2
    u32 a1 = (u32)f2bf(1.5f)   | ((u32)f2bf(-2.25f) << 16);
    u32 b1v = (u32)f2bf(0.5f)  | ((u32)f2bf(4.0f)   << 16);
    u32 a2 = (u32)f2bf(0.125f) | ((u32)f2bf(3.0f)   << 16);
    u32 b2v = (u32)f2bf(8.0f)  | ((u32)f2bf(-0.5f)  << 16);
    float t1 = hwdot2(a1, b1v, 1.0f);   // 1 + 0.75 - 9   = -7.25
    float t2 = hwdot2(a2, b2v, 0.5f);   // 0.5 + 1 - 1.5  = 0
    if (fabsf(t1 + 7.25f) < 1e-2f && fabsf(t2) < 1e-2f) f |= 2u;
#endif
    *flag = f;
  }
}

// ---------------- K1: X0 = leaky_relu(data_in @ w1.T + b1), stored packed bf16 ----------------
__global__ void __launch_bounds__(256) k_in(const void* __restrict__ din,
                                            const void* __restrict__ w1,
                                            const void* __restrict__ b1,
                                            u32* __restrict__ X0,
                                            const u32* __restrict__ flagp) {
  const u32 isf = *flagp & 1u;
  int t = blockIdx.x, tid = threadIdx.x;
  __shared__ float xs[64];
  if (isf) {
    if (tid < 64) xs[tid] = ((const float*)din)[(size_t)t * 64 + tid];
  } else {
    if (tid < 32) {
      u32 v = ((const u32*)din)[(size_t)t * 32 + tid];
      xs[2 * tid] = bflo(v); xs[2 * tid + 1] = bfhi(v);
    }
  }
  __syncthreads();
  float o[4];
#pragma unroll
  for (int r = 0; r < 4; ++r) {
    int i = tid * 4 + r;
    float a = 0.f;
    if (isf) {
      const float* wr = (const float*)w1 + (size_t)i * 64;
#pragma unroll
      for (int d = 0; d < 64; ++d) a = fmaf(wr[d], xs[d], a);
      a += ((const float*)b1)[i];
    } else {
      const u32* wr = (const u32*)w1 + (size_t)i * 32;
#pragma unroll
      for (int d = 0; d < 32; ++d) {
        u32 w = wr[d];
        a = fmaf(bflo(w), xs[2 * d], a);
        a = fmaf(bfhi(w), xs[2 * d + 1], a);
      }
      a += bf2f(((const u16*)b1)[i]);
    }
    o[r] = lrelu(a);
  }
  X0[(size_t)t * 512 + tid * 2]     = (u32)f2bf(o[0]) | ((u32)f2bf(o[1]) << 16);
  X0[(size_t)t * 512 + tid * 2 + 1] = (u32)f2bf(o[2]) | ((u32)f2bf(o[3]) << 16);
}

// ---------------- K2: persistent wavefront LSTM — 16B tagged granules + layer-skew-2 ----------------
// Granule (16 B) = [tag=t | pair2g | pair2g+1 | 0]; 256 granules per (layer,slot).
// Publish: one dwordx4 fire-and-forget LLC store per granule (5/WG/step).
// Consume: thread tid polls granule tid with ONE dwordx4 load per pass; tag
// match => payload is current (16B transaction atomicity). Per-granule retry.
// Layer-skew 2: layer l computes t = s - 2l, so x (= h of layer l-1) is
// published one step before it's needed -> PREFETCHED during the previous
// step's tail; only the intra-layer h exchange sits on the per-step spin.
// WAR (slot reuse after RING steps): per-layer epoch counters, cached horizon
// (one load certifies ~12 steps). All spins share one budget -> terminating.
__global__ void __launch_bounds__(TPB, 1) k_wave(const void* __restrict__ WihP,
                                                 const void* __restrict__ WhhP,
                                                 const void* __restrict__ bihP,
                                                 const void* __restrict__ bhhP,
                                                 const void* __restrict__ h0P,
                                                 const void* __restrict__ c0P,
                                                 const u32* __restrict__ X0,
                                                 u32* __restrict__ H5,
                                                 u32* slots, u32* epochs,
                                                 const u32* __restrict__ flagp) {
  const u32 dfl = *flagp;
  const u32 isf = dfl & 1u;
  const bool ud2 = (dfl & 2u) != 0u;
  const int tid  = threadIdx.x;
  const int lane = tid & 63;
  const int wv   = tid >> 6;
  const int wg   = blockIdx.x;

  __shared__ u32   vlds[2][64 * 17];            // [layer-sel][VIDX(word)] conflict-spread
  __shared__ u32   wlds[4 * NLR * 1024];        // [wave][row][d4][lane][4] 128 KiB
  __shared__ float zrow[80];

  // ---- load weights: rows 0..NVR-1 -> VGPRs, rows NVR..19 -> LDS ----
  u32 W[NVR][16];
#pragma unroll
  for (int i = 0; i < RPW; ++i) {
    int rr = wv * RPW + i;
    int p = rr >> 2, q = rr & 3;
    int g = wg * PAIRS + p;
    int lg = g >> 10, j = g & 1023;
    u32 tmp[16];
    if (isf) {
      const float* matf = (lane < 32) ? (const float*)WihP : (const float*)WhhP;
      const float4* s4 = (const float4*)(matf + ((size_t)(lg * 4096 + q * 1024 + j)) * 1024 + (lane & 31) * 32);
#pragma unroll
      for (int q4 = 0; q4 < 8; ++q4) {
        float4 f = s4[q4];
        tmp[q4 * 2]     = (u32)f2bf(f.x) | ((u32)f2bf(f.y) << 16);
        tmp[q4 * 2 + 1] = (u32)f2bf(f.z) | ((u32)f2bf(f.w) << 16);
      }
    } else {
      const u32* mat = (lane < 32) ? (const u32*)WihP : (const u32*)WhhP;
      const uint4* s4 = (const uint4*)(mat + ((size_t)(lg * 4096 + q * 1024 + j)) * 512 + (lane & 31) * 16);
      uint4 a0 = s4[0], a1 = s4[1], a2 = s4[2], a3 = s4[3];
      tmp[0]=a0.x; tmp[1]=a0.y; tmp[2]=a0.z;  tmp[3]=a0.w;
      tmp[4]=a1.x; tmp[5]=a1.y; tmp[6]=a1.z;  tmp[7]=a1.w;
      tmp[8]=a2.x; tmp[9]=a2.y; tmp[10]=a2.z; tmp[11]=a2.w;
      tmp[12]=a3.x;tmp[13]=a3.y;tmp[14]=a3.z; tmp[15]=a3.w;
    }
    if (i < NVR) {
#pragma unroll
      for (int d = 0; d < 16; ++d) W[i][d] = tmp[d];
    } else {
      u32* base = &wlds[(wv * NLR + (i - NVR)) * 1024];
#pragma unroll
      for (int d4 = 0; d4 < 4; ++d4) {
        uint4 v4 = make_uint4(tmp[d4*4], tmp[d4*4+1], tmp[d4*4+2], tmp[d4*4+3]);
        *(uint4*)&base[d4 * 256 + lane * 4] = v4;
      }
    }
  }

  // ---- per-unit state in wave0 registers (lane < PAIRS owns one unit) ----
  float cst = 0.f;
  float b0 = 0.f, b1g = 0.f, b2g = 0.f, b3g = 0.f;
  if (wv == 0 && lane < PAIRS) {
    int g = wg * PAIRS + lane, lg = g >> 10, j = g & 1023;
    cst = isf ? ((const float*)c0P)[lg * 1024 + j] : bf2f(((const u16*)c0P)[lg * 1024 + j]);
#pragma unroll
    for (int q = 0; q < 4; ++q) {
      int r = lg * 4096 + q * 1024 + j;
      float bb = isf ? (((const float*)bihP)[r] + ((const float*)bhhP)[r])
                     : (bf2f(((const u16*)bihP)[r]) + bf2f(((const u16*)bhhP)[r]));
      if (q == 0) b0 = bb; else if (q == 1) b1g = bb; else if (q == 2) b2g = bb; else b3g = bb;
    }
  }
  // ---- h0 -> ring slot 15 (t = -1), tag = 0xFFFFFFFF, one granule per 4 units ----
  if (tid < 5) {
    int u = wg * PAIRS + 4 * tid, lg = u >> 10, j = u & 1023;
    u32 p0, p1;
    if (isf) {
      const float* h0f = (const float*)h0P + lg * 1024 + j;
      p0 = (u32)f2bf(h0f[0]) | ((u32)f2bf(h0f[1]) << 16);
      p1 = (u32)f2bf(h0f[2]) | ((u32)f2bf(h0f[3]) << 16);
    } else {
      const u16* h0b = (const u16*)h0P + lg * 1024 + j;
      p0 = (u32)h0b[0] | ((u32)h0b[1] << 16);
      p1 = (u32)h0b[2] | ((u32)h0b[3] << 16);
    }
    llc_store4(slots + ((size_t)(lg * RING + (RING - 1)) * 256 + (j >> 2)) * 4,
               0xFFFFFFFFu, p0, p1);
  }
  // no init fence needed: tags self-synchronize (stale tag => retry)

  const int l_lo = (wg * PAIRS) >> 10;
  const int l_hi = (wg * PAIRS + PAIRS - 1) >> 10;
  const bool span = (l_hi != l_lo);

  int budget = 20000000;                        // bounded polling: never hard-hang
  int war_until0 = RING - 1;                    // publishes certified through this step
  int war_until1 = RING - 1;
  bool pf0 = false, pf1 = false;                // x prefetched for next step?

  for (int s = 0; s < WSTEPS; ++s) {
    const int t0 = s - 2 * l_lo;
    const int t1 = s - 2 * l_hi;
    const bool a0 = (t0 >= 0) && (t0 < SEQ);
    const bool a1 = span && (t1 >= 0) && (t1 < SEQ);

    // ---- layer-0 x comes from X0 (always fresh, plain loads) ----
    if (a0 && l_lo == 0) {
      u64 xv = *(const u64*)(X0 + (size_t)t0 * 512 + 2 * tid);
      vlds[0][VIDX(2 * tid)]     = (u32)xv;
      vlds[0][VIDX(2 * tid + 1)] = (u32)(xv >> 32);
    }

    // ---- critical spin: h granules (1 load/thread) + rare x-prefetch misses ----
    {
      bool h0ok = !a0, h1ok = !a1;
      bool x0ok = !a0 || (l_lo == 0) || pf0;
      bool x1ok = !a1 || pf1;
      const u32* ha0 = slots + ((size_t)(l_lo * RING + ((t0 - 1) & 15)) * 256 + tid) * 4;
      const u32* ha1 = slots + ((size_t)(l_hi * RING + ((t1 - 1) & 15)) * 256 + tid) * 4;
      const u32* xa0 = (l_lo > 0)
          ? slots + ((size_t)((l_lo - 1) * RING + (t0 & 15)) * 256 + tid) * 4 : ha0;
      const u32* xa1 = slots + ((size_t)(l_lo * RING + (t1 & 15)) * 256 + tid) * 4;
      const u32 eh0 = (u32)(t0 - 1), eh1 = (u32)(t1 - 1);
      const u32 ex0 = (u32)t0, ex1 = (u32)t1;
      int miss = 0;
      while (!__all(h0ok && h1ok && x0ok && x1ok)) {
        u32x4_t wh0, wh1, wx0, wx1;
        if (!h0ok) wh0 = llc_load4(ha0);
        if (!h1ok) wh1 = llc_load4(ha1);
        if (!x0ok) wx0 = llc_load4(xa0);
        if (!x1ok) wx1 = llc_load4(xa1);
        vm_drain();
        if (!h0ok && wh0.x == eh0) {
          vlds[0][VIDX(512 + 2 * tid)] = wh0.y; vlds[0][VIDX(513 + 2 * tid)] = wh0.z; h0ok = true;
        }
        if (!h1ok && wh1.x == eh1) {
          vlds[1][VIDX(512 + 2 * tid)] = wh1.y; vlds[1][VIDX(513 + 2 * tid)] = wh1.z; h1ok = true;
        }
        if (!x0ok && wx0.x == ex0) {
          vlds[0][VIDX(2 * tid)] = wx0.y; vlds[0][VIDX(2 * tid + 1)] = wx0.z; x0ok = true;
        }
        if (!x1ok && wx1.x == ex1) {
          vlds[1][VIDX(2 * tid)] = wx1.y; vlds[1][VIDX(2 * tid + 1)] = wx1.z; x1ok = true;
        }
        if (--budget < 0) break;
        if (++miss >= 16) __builtin_amdgcn_s_sleep(1);   // stragglers only
      }
    }
    __syncthreads();            // B: vlds ready

    // ---- 20 row dots per wave (12 VGPR rows + 8 LDS rows) ----
    {
      int curl = -1;
      u32 vreg[16];
#pragma unroll
      for (int i = 0; i < RPW; ++i) {
        int rr = wv * RPW + i;
        int p = rr >> 2;
        int g = wg * PAIRS + p;
        int lg = g >> 10;
        int t = s - 2 * lg;
        if (t >= 0 && t < SEQ) {
          if (lg != curl) {
            curl = lg;
            const u32* vb = &vlds[lg - l_lo][lane * 17];
#pragma unroll
            for (int d = 0; d < 16; ++d) vreg[d] = vb[d];
          }
          float a0 = 0.f, a1 = 0.f, a2 = 0.f, a3 = 0.f;
          if (i < NVR) {
            if (ud2) {
#pragma unroll
              for (int d = 0; d < 16; d += 4) {
                a0 = hwdot2(W[i][d],   vreg[d],   a0);
                a1 = hwdot2(W[i][d+1], vreg[d+1], a1);
                a2 = hwdot2(W[i][d+2], vreg[d+2], a2);
                a3 = hwdot2(W[i][d+3], vreg[d+3], a3);
              }
            } else {
#pragma unroll
              for (int d = 0; d < 16; d += 4) {
                a0 = fmaf(bflo(W[i][d]),   bflo(vreg[d]),   a0);
                a0 = fmaf(bfhi(W[i][d]),   bfhi(vreg[d]),   a0);
                a1 = fmaf(bflo(W[i][d+1]), bflo(vreg[d+1]), a1);
                a1 = fmaf(bfhi(W[i][d+1]), bfhi(vreg[d+1]), a1);
                a2 = fmaf(bflo(W[i][d+2]), bflo(vreg[d+2]), a2);
                a2 = fmaf(bfhi(W[i][d+2]), bfhi(vreg[d+2]), a2);
                a3 = fmaf(bflo(W[i][d+3]), bflo(vreg[d+3]), a3);
                a3 = fmaf(bfhi(W[i][d+3]), bfhi(vreg[d+3]), a3);
              }
            }
          } else {
            const uint4* wl = (const uint4*)&wlds[(wv * NLR + (i - NVR)) * 1024 + lane * 4];
#pragma unroll
            for (int d4 = 0; d4 < 4; ++d4) {
              uint4 w4 = wl[d4 * 64];
              if (ud2) {
                a0 = hwdot2(w4.x, vreg[d4*4+0], a0);
                a1 = hwdot2(w4.y, vreg[d4*4+1], a1);
                a2 = hwdot2(w4.z, vreg[d4*4+2], a2);
                a3 = hwdot2(w4.w, vreg[d4*4+3], a3);
              } else {
                a0 = fmaf(bflo(w4.x), bflo(vreg[d4*4+0]), a0);
                a0 = fmaf(bfhi(w4.x), bfhi(vreg[d4*4+0]), a0);
                a1 = fmaf(bflo(w4.y), bflo(vreg[d4*4+1]), a1);
                a1 = fmaf(bfhi(w4.y), bfhi(vreg[d4*4+1]), a1);
                a2 = fmaf(bflo(w4.z), bflo(vreg[d4*4+2]), a2);
                a2 = fmaf(bfhi(w4.z), bfhi(vreg[d4*4+2]), a2);
                a3 = fmaf(bflo(w4.w), bflo(vreg[d4*4+3]), a3);
                a3 = fmaf(bfhi(w4.w), bfhi(vreg[d4*4+3]), a3);
              }
            }
          }
          float r = (a0 + a1) + (a2 + a3);
          r += __shfl_xor(r, 32);
          r += __shfl_xor(r, 16);
          r += __shfl_xor(r, 8);
          r += __shfl_xor(r, 4);
          r += __shfl_xor(r, 2);
          r += __shfl_xor(r, 1);
          if (lane == 0) zrow[rr] = r;
        }
      }
    }
    __syncthreads();            // C: zrow ready, vlds free to rewrite

    // ---- wave0: WAR guard (cached horizon) + gates + granule publish ----
    if (wv == 0) {
      if ((l_lo + 1) < NL && s > war_until0) {
        for (;;) {
          u32 E = agent_load(&epochs[(l_lo + 1) * 32]);
          int until = (int)(E / 52u) + 12;
          if (until >= s) { war_until0 = until; break; }
          if (--budget < 0) { war_until0 = s; break; }
          __builtin_amdgcn_s_sleep(2);
        }
      }
      if (span && (l_hi + 1) < NL && s > war_until1) {
        for (;;) {
          u32 E = agent_load(&epochs[(l_hi + 1) * 32]);
          int until = (int)(E / 52u) + 12;
          if (until >= s) { war_until1 = until; break; }
          if (--budget < 0) { war_until1 = s; break; }
          __builtin_amdgcn_s_sleep(2);
        }
      }
      u16 hb = 0;
      int g = wg * PAIRS + lane;     // valid for lane < PAIRS
      int lg = g >> 10;
      int t = s - 2 * lg;
      bool act = (lane < PAIRS) && (t >= 0) && (t < SEQ);
      if (act) {
        float zi = zrow[lane * 4 + 0] + b0;
        float zf = zrow[lane * 4 + 1] + b1g;
        float zg = zrow[lane * 4 + 2] + b2g;
        float zo = zrow[lane * 4 + 3] + b3g;
        float ig = sigm(zi), fg = sigm(zf), gg = tanh_f(zg), og = sigm(zo);
        float c = fg * cst + ig * gg;
        cst = c;
        hb = f2bf(og * tanh_f(c));
      }
      u16 hnb = (u16)__shfl_xor((int)hb, 1);
      u32 v = (u32)hb | ((u32)hnb << 16);        // even lanes hold their pair
      u32 pa = (u32)__shfl((int)v, (4 * lane) & 63);
      u32 pb = (u32)__shfl((int)v, (4 * lane + 2) & 63);
      if (lane < 5) {                            // one granule per 4 owned units
        int u = wg * PAIRS + 4 * lane, lg2 = u >> 10, j2 = u & 1023;
        int tg = s - 2 * lg2;
        if (tg >= 0 && tg < SEQ)
          llc_store4(slots + ((size_t)(lg2 * RING + (tg & 15)) * 256 + (j2 >> 2)) * 4,
                     (u32)tg, pa, pb);
      }
      if (act && !(lane & 1) && lg == NL - 1)
        H5[(size_t)t * 512 + ((g & 1023) >> 1)] = v;
      if (lane == 0) {               // step s complete for owned layers
        epoch_add(&epochs[l_lo * 32]);
        if (span) epoch_add(&epochs[l_hi * 32]);
      }
    }

    // ---- all waves: prefetch next step's x granules (overlaps publish travel) ----
    {
      const int tn0 = (s + 1) - 2 * l_lo;
      const int tn1 = (s + 1) - 2 * l_hi;
      const bool p0 = (l_lo > 0) && (tn0 >= 0) && (tn0 < SEQ);
      const bool p1 = span && (tn1 >= 0) && (tn1 < SEQ);
      pf0 = false; pf1 = false;
      if (p0 | p1) {
        u32x4_t w0, w1;
        if (p0) w0 = llc_load4(slots + ((size_t)((l_lo - 1) * RING + (tn0 & 15)) * 256 + tid) * 4);
        if (p1) w1 = llc_load4(slots + ((size_t)(l_lo * RING + (tn1 & 15)) * 256 + tid) * 4);
        vm_drain();
        if (p0 && w0.x == (u32)tn0) {
          vlds[0][VIDX(2 * tid)] = w0.y; vlds[0][VIDX(2 * tid + 1)] = w0.z; pf0 = true;
        }
        if (p1 && w1.x == (u32)tn1) {
          vlds[1][VIDX(2 * tid)] = w1.y; vlds[1][VIDX(2 * tid + 1)] = w1.z; pf1 = true;
        }
      }
    }
  }
}

// ---------------- K3: out = tanh(leaky_relu(h5) @ w2.T + b2) ----------------
__global__ void __launch_bounds__(256) k_out(const u32* __restrict__ H5,
                                             const void* __restrict__ w2,
                                             const void* __restrict__ b2,
                                             void* __restrict__ out,
                                             const u32* __restrict__ flagp) {
  const u32 isf = *flagp & 1u;
  int t = blockIdx.x, tid = threadIdx.x;
  __shared__ float hs[1024];
  __shared__ float part[256];
#pragma unroll
  for (int r = 0; r < 2; ++r) {
    int idx = tid + r * 256;
    u32 v = H5[(size_t)t * 512 + idx];
    hs[2 * idx]     = lrelu(bflo(v));
    hs[2 * idx + 1] = lrelu(bfhi(v));
  }
  __syncthreads();
  int n = tid & 63, qq = tid >> 6;
  float a = 0.f;
  if (isf) {
    const float* wr = (const float*)w2 + (size_t)n * 1024 + qq * 256;
    const float* hb = &hs[qq * 256];
#pragma unroll
    for (int d = 0; d < 256; ++d) a = fmaf(wr[d], hb[d], a);
  } else {
    const u32* wr = (const u32*)w2 + (size_t)n * 512 + qq * 128;
    const float* hb = &hs[qq * 256];
#pragma unroll
    for (int d = 0; d < 128; ++d) {
      u32 w = wr[d];
      a = fmaf(bflo(w), hb[2 * d], a);
      a = fmaf(bfhi(w), hb[2 * d + 1], a);
    }
  }
  part[tid] = a;
  __syncthreads();
  if (tid < 64) {
    float bb = isf ? ((const float*)b2)[tid] : bf2f(((const u16*)b2)[tid]);
    float y = part[tid] + part[tid + 64] + part[tid + 128] + part[tid + 192] + bb;
    float r = tanh_f(y);
    if (isf) ((float*)out)[(size_t)t * 64 + tid] = r;
    else     ((u16*)out)[(size_t)t * 64 + tid] = f2bf(r);
  }
}

// ---------------- launcher ----------------
extern "C" void kernel_launch(void* const* d_in, const int* in_sizes, int n_in,
                              void* d_out, int out_size, void* d_ws, size_t ws_size,
                              hipStream_t stream) {
  (void)in_sizes; (void)n_in; (void)out_size;
  if (ws_size < WS_NEED) return;

  const void* din = d_in[0];
  const void* w1  = d_in[1];
  const void* b1  = d_in[2];
  const void* Wih = d_in[3];
  const void* Whh = d_in[4];
  const void* bih = d_in[5];
  const void* bhh = d_in[6];
  const void* w2  = d_in[7];
  const void* b2  = d_in[8];
  const void* h0  = d_in[9];
  const void* c0  = d_in[10];

  char* ws = (char*)d_ws;
  u32* X0     = (u32*)(ws + WS_X0);
  u32* H5     = (u32*)(ws + WS_H5);
  u32* slot   = (u32*)(ws + WS_SLOT);
  u32* epochs = (u32*)(ws + WS_SYNC);
  u32* dflag  = (u32*)(ws + WS_SYNC + 2048);

  // slot tags must not alias any valid tag (t in [0,SEQ) or 0xFFFFFFFF):
  // 0xAAAAAAAA is neither. memset per launch kills cross-run tag aliasing.
  hipMemsetAsync(slot, 0xAA, (size_t)NL * RING * 256 * 16, stream);
  hipMemsetAsync(epochs, 0, 4096, stream);     // epochs + dtype word
  k_detect<<<1, 64, 0, stream>>>((const u32*)w1, dflag);
  k_in  <<<SEQ, 256, 0, stream>>>(din, w1, b1, X0, dflag);
  k_wave<<<NWG, TPB, 0, stream>>>(Wih, Whh, bih, bhh, h0, c0, X0, H5, slot, epochs, dflag);
  k_out <<<SEQ, 256, 0, stream>>>(H5, w2, b2, d_out, dflag);
}